// Round 1
// baseline (613.861 us; speedup 1.0000x reference)
//
#include <hip/hip_runtime.h>

// Problem constants (from reference)
#define N_NODES 10000
#define AS 8
#define NE 320000
#define NB 32
#define SIZE1 80000   // N_NODES*AS1
#define SIZE2 80000   // N_NODES*AS2
// out: (B, SIZE2) fp32 = 2,560,000 floats

// Kernel 1: out[b, s] = bias[s]  (d_out is poisoned before every call)
__global__ __launch_bounds__(256) void init_out_kernel(const float* __restrict__ bias,
                                                       float* __restrict__ out) {
  int idx = blockIdx.x * 256 + threadIdx.x;        // float4 index
  const int total4 = (NB * SIZE2) / 4;             // 640,000
  if (idx < total4) {
    const float4* b4 = (const float4*)bias;
    float4* o4 = (float4*)out;
    o4[idx] = b4[idx % (SIZE2 / 4)];
  }
}

// Kernel 2: edge scatter. One 256-thread block per edge iteration.
// thread t -> (b = t>>3, j = t&7). Per edge:
//   LDS stage values[e] (64 f) and x[:, col, :] (256 f), then
//   acc = sum_i xs[b][i] * vs[i][j];  atomicAdd(out[b, row*8+j], acc)
__global__ __launch_bounds__(256) void edge_scatter_kernel(const float* __restrict__ x,
                                                           const float* __restrict__ vals,
                                                           const int* __restrict__ idxs,
                                                           float* __restrict__ out) {
  __shared__ float vs[2][64];
  __shared__ float xs[2][256];
  const int t = threadIdx.x;
  const int b = t >> 3;
  const int j = t & 7;
  int buf = 0;
  for (int e = blockIdx.x; e < NE; e += gridDim.x, buf ^= 1) {
    const int row = idxs[e];        // uniform -> scalar load
    const int col = idxs[NE + e];   // uniform -> scalar load
    if (t < 64) vs[buf][t] = vals[(size_t)e * 64 + t];
    xs[buf][t] = x[b * SIZE1 + col * 8 + j];
    __syncthreads();  // double-buffered: one barrier per edge is sufficient
    float acc = 0.f;
#pragma unroll
    for (int i = 0; i < 8; ++i)
      acc += xs[buf][(b << 3) + i] * vs[buf][i * 8 + j];
    atomicAdd(&out[b * SIZE2 + row * 8 + j], acc);
  }
}

extern "C" void kernel_launch(void* const* d_in, const int* in_sizes, int n_in,
                              void* d_out, int out_size, void* d_ws, size_t ws_size,
                              hipStream_t stream) {
  const float* x    = (const float*)d_in[0];  // (B, SIZE1, 1)
  const float* vals = (const float*)d_in[1];  // (E, 8, 8)
  const float* bias = (const float*)d_in[2];  // (SIZE2,)
  const int*   idxs = (const int*)d_in[3];    // (2, E): rows then cols
  float* out = (float*)d_out;

  // 1) out = bias (broadcast over batch)
  {
    const int total4 = (NB * SIZE2) / 4;
    const int grid = (total4 + 255) / 256;
    init_out_kernel<<<grid, 256, 0, stream>>>(bias, out);
  }
  // 2) scatter-accumulate edges
  {
    const int grid = 8192;  // grid-stride over 320k edges, ~39 edges/block
    edge_scatter_kernel<<<grid, 256, 0, stream>>>(x, vals, idxs, out);
  }
}

// Round 2
// 347.796 us; speedup vs baseline: 1.7650x; 1.7650x over previous
//
#include <hip/hip_runtime.h>
#include <stddef.h>

#define N_NODES 10000
#define NE 320000
#define NB 32
#define SIZE1 80000
#define SIZE2 80000

// d_ws layout (ints):
//   [0, 640000)            pairs: int2[NE] {col, e}   (8B aligned at offset 0)
//   [640000, 650000)       counts[N_NODES]
//   [650001-? ] offsets -- see below
//   offsets: [650000, 660001)  (10001 ints)
//   cursor:  [660002, 670002)  (keep even alignment for safety)
#define WS_PAIRS   0
#define WS_COUNTS  640000
#define WS_OFFSETS 650000
#define WS_CURSOR  660002

__global__ __launch_bounds__(256) void count_kernel(const int* __restrict__ idxs,
                                                    int* __restrict__ counts) {
  int e = blockIdx.x * 256 + threadIdx.x;
  if (e < NE) atomicAdd(&counts[idxs[e]], 1);
}

// Single-block chunked exclusive scan of counts -> offsets (+ cursor copy).
__global__ __launch_bounds__(256) void scan_kernel(const int* __restrict__ counts,
                                                   int* __restrict__ offsets,
                                                   int* __restrict__ cursor) {
  __shared__ int s[256];
  __shared__ int running;
  const int t = threadIdx.x;
  if (t == 0) running = 0;
  __syncthreads();
  for (int base = 0; base < N_NODES; base += 256) {
    int i = base + t;
    int c = (i < N_NODES) ? counts[i] : 0;
    s[t] = c;
    __syncthreads();
#pragma unroll
    for (int d = 1; d < 256; d <<= 1) {
      int v = (t >= d) ? s[t - d] : 0;
      __syncthreads();
      s[t] += v;
      __syncthreads();
    }
    int excl = running + s[t] - c;
    if (i < N_NODES) { offsets[i] = excl; cursor[i] = excl; }
    __syncthreads();
    if (t == 0) running += s[255];
    __syncthreads();
  }
  if (t == 0) offsets[N_NODES] = running;
}

__global__ __launch_bounds__(256) void scatter_kernel(const int* __restrict__ idxs,
                                                      int* __restrict__ cursor,
                                                      int2* __restrict__ pairs) {
  int e = blockIdx.x * 256 + threadIdx.x;
  if (e < NE) {
    int r = idxs[e];
    int c = idxs[NE + e];
    int pos = atomicAdd(&cursor[r], 1);
    pairs[pos] = make_int2(c, e);
  }
}

// One block per node. thread t -> (b = t>>3, j = t&7).
// Per edge: stage values[e] (64 f) + x[:, col, :] (256 f) into LDS
// (double-buffered, 1 barrier/edge), accumulate in registers; single
// write per output element at the end, fused with bias.
__global__ __launch_bounds__(256) void gather_kernel(const float* __restrict__ x,
                                                     const float* __restrict__ vals,
                                                     const float* __restrict__ bias,
                                                     const int* __restrict__ offsets,
                                                     const int2* __restrict__ pairs,
                                                     float* __restrict__ out) {
  __shared__ float vs[2][64];
  __shared__ float xs[2][256];
  const int n = blockIdx.x;
  const int t = threadIdx.x;
  const int b = t >> 3;
  const int j = t & 7;
  const int beg = offsets[n];
  const int end = offsets[n + 1];

  auto stage = [&](int bf, int2 p) {
    if (t < 64) {
      int bb = t >> 1, half = (t & 1) * 4;
      float4 v = *(const float4*)&x[(size_t)bb * SIZE1 + p.x * 8 + half];
      *(float4*)&xs[bf][bb * 8 + half] = v;
    } else if (t < 80) {
      int k4 = t - 64;
      float4 v = ((const float4*)(vals + (size_t)p.y * 64))[k4];
      *(float4*)&vs[bf][k4 * 4] = v;
    }
  };

  float acc = 0.f;
  if (beg < end) {
    int buf = 0;
    int2 p = pairs[beg];
    stage(buf, p);
    for (int k = beg; k < end; ++k) {
      __syncthreads();  // staging of `buf` done; all threads done with buf^1 compute
      if (k + 1 < end) {
        p = pairs[k + 1];
        stage(buf ^ 1, p);
      }
#pragma unroll
      for (int i = 0; i < 8; ++i)
        acc += xs[buf][(b << 3) + i] * vs[buf][i * 8 + j];
      buf ^= 1;
    }
  }
  out[(size_t)b * SIZE2 + n * 8 + j] = acc + bias[n * 8 + j];
}

extern "C" void kernel_launch(void* const* d_in, const int* in_sizes, int n_in,
                              void* d_out, int out_size, void* d_ws, size_t ws_size,
                              hipStream_t stream) {
  const float* x    = (const float*)d_in[0];  // (B, SIZE1, 1)
  const float* vals = (const float*)d_in[1];  // (E, 8, 8)
  const float* bias = (const float*)d_in[2];  // (SIZE2,)
  const int*   idxs = (const int*)d_in[3];    // (2, E): rows then cols
  float* out = (float*)d_out;

  int* ws = (int*)d_ws;
  int2* pairs  = (int2*)(ws + WS_PAIRS);
  int* counts  = ws + WS_COUNTS;
  int* offsets = ws + WS_OFFSETS;
  int* cursor  = ws + WS_CURSOR;

  // counts must be zeroed every call (ws is poisoned to 0xAA)
  hipMemsetAsync(counts, 0, N_NODES * sizeof(int), stream);

  const int egrid = (NE + 255) / 256;  // 1250
  count_kernel<<<egrid, 256, 0, stream>>>(idxs, counts);
  scan_kernel<<<1, 256, 0, stream>>>(counts, offsets, cursor);
  scatter_kernel<<<egrid, 256, 0, stream>>>(idxs, cursor, pairs);
  gather_kernel<<<N_NODES, 256, 0, stream>>>(x, vals, bias, offsets, pairs, out);
}

// Round 3
// 287.784 us; speedup vs baseline: 2.1331x; 1.2085x over previous
//
#include <hip/hip_runtime.h>
#include <stddef.h>

#define N_NODES 10000
#define NE 320000
#define NB 32
#define SIZE1 80000
#define SIZE2 80000

// d_ws layout (int offsets)
#define WS_PAIRS   0          // int2[NE] -> 640000 ints
#define WS_COUNTS  640000     // 10000 ints
#define WS_OFFSETS 650000     // 10001 ints
#define WS_CURSOR  660002     // 10000 ints
#define WS_BSUMS   670016     // 64 ints
#define WS_XT      680000     // bf16 xt[N_NODES][32][8] = 2.56M bf16 = 1.28M ints
// total ~1.96M ints = 7.84 MB of ws

typedef short short8 __attribute__((ext_vector_type(8)));
typedef float floatx4 __attribute__((ext_vector_type(4)));
union FragU { short8 v; ushort us[8]; uint4 u4; };

__device__ inline ushort f2bf(float f) {
  union { float f; unsigned u; } c; c.f = f;
  unsigned u = c.u;
  u += 0x7fffu + ((u >> 16) & 1u);   // round-to-nearest-even
  return (ushort)(u >> 16);
}

// x (B, SIZE1) fp32  ->  xt[n][b][i] bf16 (512 B per node, contiguous)
__global__ __launch_bounds__(256) void transpose_x_kernel(const float* __restrict__ x,
                                                          ushort* __restrict__ xt) {
  __shared__ float s[32 * 260];  // [b][nl*8+i], row stride 260 (16B-aligned rows, few conflicts)
  const int t = threadIdx.x;
  const int n0 = blockIdx.x * 32;
  // load 32 b-rows x 256 floats, coalesced float4
#pragma unroll
  for (int it = 0; it < 8; ++it) {
    int idx = it * 256 + t;            // [0,2048)
    int b = idx >> 6, q = idx & 63;
    int base = n0 * 8 + q * 4;
    float4 v = make_float4(0.f, 0.f, 0.f, 0.f);
    if (base < SIZE1) v = *(const float4*)&x[(size_t)b * SIZE1 + base];
    *(float4*)&s[b * 260 + q * 4] = v;
  }
  __syncthreads();
  // write xt[n][b][0..8) as 8 bf16 = 16 B per thread-item, coalesced over b
#pragma unroll
  for (int r = 0; r < 4; ++r) {
    int p = r * 256 + t;               // [0,1024)
    int nl = p >> 5, b = p & 31;
    int n = n0 + nl;
    if (n < N_NODES) {
      FragU f;
      const float* row = &s[b * 260 + nl * 8];
#pragma unroll
      for (int i = 0; i < 8; ++i) f.us[i] = f2bf(row[i]);
      *(uint4*)&xt[(size_t)n * 256 + b * 8] = f.u4;
    }
  }
}

__global__ __launch_bounds__(256) void count_kernel(const int* __restrict__ idxs,
                                                    int* __restrict__ counts) {
  int e = blockIdx.x * 256 + threadIdx.x;
  if (e < NE) atomicAdd(&counts[idxs[e]], 1);
}

// 40 blocks: block-local exclusive scan into offsets, block totals into bsums
__global__ __launch_bounds__(256) void scanA_kernel(const int* __restrict__ counts,
                                                    int* __restrict__ offsets,
                                                    int* __restrict__ bsums) {
  __shared__ int s[256];
  const int t = threadIdx.x;
  const int i = blockIdx.x * 256 + t;
  int c = (i < N_NODES) ? counts[i] : 0;
  s[t] = c;
  __syncthreads();
#pragma unroll
  for (int d = 1; d < 256; d <<= 1) {
    int v = (t >= d) ? s[t - d] : 0;
    __syncthreads();
    s[t] += v;
    __syncthreads();
  }
  if (i < N_NODES) offsets[i] = s[t] - c;
  if (t == 255) bsums[blockIdx.x] = s[255];
}

// 40 blocks: add prefix of block sums, produce final offsets + cursor copy
__global__ __launch_bounds__(256) void scanC_kernel(int* __restrict__ offsets,
                                                    int* __restrict__ cursor,
                                                    const int* __restrict__ bsums) {
  const int t = threadIdx.x;
  const int nb = blockIdx.x;
  const int i = nb * 256 + t;
  int p = 0;
  for (int w = 0; w < nb; ++w) p += bsums[w];
  if (i < N_NODES) {
    int v = offsets[i] + p;
    offsets[i] = v;
    cursor[i] = v;
  }
  if (i == 0) offsets[N_NODES] = NE;
}

__global__ __launch_bounds__(256) void scatter_kernel(const int* __restrict__ idxs,
                                                      int* __restrict__ cursor,
                                                      int2* __restrict__ pairs) {
  int e = blockIdx.x * 256 + threadIdx.x;
  if (e < NE) {
    int r = idxs[e];
    int c = idxs[NE + e];
    int pos = atomicAdd(&cursor[r], 1);
    pairs[pos] = make_int2(c, e);
  }
}

// One wave per node. LDS-free, barrier-free MFMA gather.
// D[m][n] tile: m = b (two halves of 16), n = j (8 of 16 used), k = i (8 of 32 used).
// A[m=lane&15][k=quad*8+v]: quad==0 lanes load xt[col][b][0..8) as one dwordx4.
// B[n=lane&15][k=quad*8+v]: lanes 0..7 gather vals[e][v][j] (stride-8) + cvt bf16.
// All other lanes hold zeros -> k>=8 / n>=8 contribute nothing.
__global__ __launch_bounds__(256) void gather_mfma_kernel(const ushort* __restrict__ xt,
                                                          const float* __restrict__ vals,
                                                          const float* __restrict__ bias,
                                                          const int* __restrict__ offsets,
                                                          const int2* __restrict__ pairs,
                                                          float* __restrict__ out) {
  const int t = threadIdx.x;
  const int lane = t & 63;
  const int n = blockIdx.x * 4 + (t >> 6);   // 2500*4 = 10000 exactly
  const int quad = lane >> 4;
  const int nn = lane & 15;
  const int beg = offsets[n];
  const int end = offsets[n + 1];

  floatx4 acc0 = {0.f, 0.f, 0.f, 0.f};
  floatx4 acc1 = {0.f, 0.f, 0.f, 0.f};

  FragU a0, a1, bf;
  a0.u4 = make_uint4(0, 0, 0, 0);
  a1.u4 = make_uint4(0, 0, 0, 0);
  bf.u4 = make_uint4(0, 0, 0, 0);

  for (int k = beg; k < end; ++k) {
    int2 p = pairs[k];                        // wave-uniform
    if (quad == 0) {
      const ushort* xrow = xt + (size_t)p.x * 256;
      a0.u4 = *(const uint4*)(xrow + nn * 8);          // b = nn
      a1.u4 = *(const uint4*)(xrow + (16 + nn) * 8);   // b = 16 + nn
      if (nn < 8) {
        const float* vp = vals + (size_t)p.y * 64 + nn;  // column j = nn
#pragma unroll
        for (int v = 0; v < 8; ++v) bf.us[v] = f2bf(vp[v * 8]);
      }
    }
    acc0 = __builtin_amdgcn_mfma_f32_16x16x32_bf16(a0.v, bf.v, acc0, 0, 0, 0);
    acc1 = __builtin_amdgcn_mfma_f32_16x16x32_bf16(a1.v, bf.v, acc1, 0, 0, 0);
  }

  // C/D layout: col(j) = lane&15, row(m) = quad*4 + reg  [HW-verified]
  if (nn < 8) {
    float bz = bias[n * 8 + nn];
#pragma unroll
    for (int r = 0; r < 4; ++r) {
      out[(size_t)(quad * 4 + r) * SIZE2 + n * 8 + nn] = acc0[r] + bz;
      out[(size_t)(16 + quad * 4 + r) * SIZE2 + n * 8 + nn] = acc1[r] + bz;
    }
  }
}

extern "C" void kernel_launch(void* const* d_in, const int* in_sizes, int n_in,
                              void* d_out, int out_size, void* d_ws, size_t ws_size,
                              hipStream_t stream) {
  const float* x    = (const float*)d_in[0];
  const float* vals = (const float*)d_in[1];
  const float* bias = (const float*)d_in[2];
  const int*   idxs = (const int*)d_in[3];
  float* out = (float*)d_out;

  int* ws = (int*)d_ws;
  int2* pairs    = (int2*)(ws + WS_PAIRS);
  int* counts    = ws + WS_COUNTS;
  int* offsets   = ws + WS_OFFSETS;
  int* cursor    = ws + WS_CURSOR;
  int* bsums     = ws + WS_BSUMS;
  ushort* xt     = (ushort*)(ws + WS_XT);

  hipMemsetAsync(counts, 0, N_NODES * sizeof(int), stream);

  transpose_x_kernel<<<(N_NODES + 31) / 32, 256, 0, stream>>>(x, xt);

  const int egrid = (NE + 255) / 256;          // 1250
  const int ngrid = (N_NODES + 255) / 256;     // 40
  count_kernel<<<egrid, 256, 0, stream>>>(idxs, counts);
  scanA_kernel<<<ngrid, 256, 0, stream>>>(counts, offsets, bsums);
  scanC_kernel<<<ngrid, 256, 0, stream>>>(offsets, cursor, bsums);
  scatter_kernel<<<egrid, 256, 0, stream>>>(idxs, cursor, pairs);

  gather_mfma_kernel<<<N_NODES / 4, 256, 0, stream>>>(xt, vals, bias, offsets, pairs, out);
}

// Round 4
// 203.012 us; speedup vs baseline: 3.0238x; 1.4176x over previous
//
#include <hip/hip_runtime.h>
#include <stddef.h>

#define N_NODES 10000
#define NE 320000
#define NB 32
#define SIZE1 80000
#define SIZE2 80000

// d_ws layout (int offsets)
#define WS_PAIRS   0          // int2[NE] -> 640000 ints
#define WS_COUNTS  640000     // 10000 ints
#define WS_OFFSETS 650000     // 10001 ints
#define WS_CURSOR  660002     // 10000 ints
#define WS_BSUMS   670016     // 64 ints
#define WS_XT      680000     // bf16 xt[N_NODES][32][8] = 1.28M ints

typedef short short8 __attribute__((ext_vector_type(8)));
typedef float floatx4 __attribute__((ext_vector_type(4)));
union FragU { short8 v; ushort us[8]; uint4 u4; };

__device__ inline ushort f2bf(float f) {
  union { float f; unsigned u; } c; c.f = f;
  unsigned u = c.u;
  u += 0x7fffu + ((u >> 16) & 1u);   // round-to-nearest-even
  return (ushort)(u >> 16);
}

// Fused: edge-count histogram (all 1250 blocks) + x fp32->bf16 transpose
// into xt[n][b][i] (blocks < 313, 32 nodes each).
__global__ __launch_bounds__(256) void prep_kernel(const float* __restrict__ x,
                                                   ushort* __restrict__ xt,
                                                   const int* __restrict__ idxs,
                                                   int* __restrict__ counts) {
  {
    int e = blockIdx.x * 256 + threadIdx.x;
    if (e < NE) atomicAdd(&counts[idxs[e]], 1);
  }
  if (blockIdx.x >= 313) return;   // block-uniform exit before any barrier
  __shared__ float s[32 * 260];    // [b][nl*8+i], padded row stride
  const int t = threadIdx.x;
  const int n0 = blockIdx.x * 32;
#pragma unroll
  for (int it = 0; it < 8; ++it) {
    int idx = it * 256 + t;            // [0,2048)
    int b = idx >> 6, q = idx & 63;
    int base = n0 * 8 + q * 4;
    float4 v = make_float4(0.f, 0.f, 0.f, 0.f);
    if (base < SIZE1) v = *(const float4*)&x[(size_t)b * SIZE1 + base];
    *(float4*)&s[b * 260 + q * 4] = v;
  }
  __syncthreads();
#pragma unroll
  for (int r = 0; r < 4; ++r) {
    int p = r * 256 + t;               // [0,1024)
    int nl = p >> 5, b = p & 31;
    int n = n0 + nl;
    if (n < N_NODES) {
      FragU f;
      const float* row = &s[b * 260 + nl * 8];
#pragma unroll
      for (int i = 0; i < 8; ++i) f.us[i] = f2bf(row[i]);
      *(uint4*)&xt[(size_t)n * 256 + b * 8] = f.u4;
    }
  }
}

__global__ __launch_bounds__(256) void scanA_kernel(const int* __restrict__ counts,
                                                    int* __restrict__ offsets,
                                                    int* __restrict__ bsums) {
  __shared__ int s[256];
  const int t = threadIdx.x;
  const int i = blockIdx.x * 256 + t;
  int c = (i < N_NODES) ? counts[i] : 0;
  s[t] = c;
  __syncthreads();
#pragma unroll
  for (int d = 1; d < 256; d <<= 1) {
    int v = (t >= d) ? s[t - d] : 0;
    __syncthreads();
    s[t] += v;
    __syncthreads();
  }
  if (i < N_NODES) offsets[i] = s[t] - c;
  if (t == 255) bsums[blockIdx.x] = s[255];
}

__global__ __launch_bounds__(256) void scanC_kernel(int* __restrict__ offsets,
                                                    int* __restrict__ cursor,
                                                    const int* __restrict__ bsums) {
  const int t = threadIdx.x;
  const int nb = blockIdx.x;
  const int i = nb * 256 + t;
  int p = 0;
  for (int w = 0; w < nb; ++w) p += bsums[w];
  if (i < N_NODES) {
    int v = offsets[i] + p;
    offsets[i] = v;
    cursor[i] = v;
  }
  if (i == 0) offsets[N_NODES] = NE;
}

__global__ __launch_bounds__(256) void scatter_kernel(const int* __restrict__ idxs,
                                                      int* __restrict__ cursor,
                                                      int2* __restrict__ pairs) {
  int e = blockIdx.x * 256 + threadIdx.x;
  if (e < NE) {
    int r = idxs[e];
    int c = idxs[NE + e];
    int pos = atomicAdd(&cursor[r], 1);
    pairs[pos] = make_int2(c, e);
  }
}

// One wave per node; 8 edges per loop iteration (two 4-edge MFMA slots).
// K=32 packs 4 edges: quad q's k-slots 8q..8q+7 hold edge (k_base+q).
// A[m=lane&15][k=quad*8+v] = xt[col(edge_quad)][b=m][i=v]  (1 dwordx4/lane/slot)
// B[n=lane&15][k=quad*8+v] = vals[e(edge_quad)][i=v][j=n]  (8 dwords, nn<8 lanes)
// Invalid tail slots: zero the B fragment (uniform per quad) -> contributes 0.
__global__ __launch_bounds__(256) void gather_mfma_kernel(const ushort* __restrict__ xt,
                                                          const float* __restrict__ vals,
                                                          const float* __restrict__ bias,
                                                          const int* __restrict__ offsets,
                                                          const int2* __restrict__ pairs,
                                                          float* __restrict__ out) {
  const int t = threadIdx.x;
  const int lane = t & 63;
  const int n = blockIdx.x * 4 + (t >> 6);   // 2500*4 = 10000
  const int quad = lane >> 4;
  const int nn = lane & 15;
  const int beg = offsets[n];
  const int end = offsets[n + 1];

  floatx4 acc0 = {0.f, 0.f, 0.f, 0.f};
  floatx4 acc1 = {0.f, 0.f, 0.f, 0.f};

  for (int k = beg; k < end; k += 8) {
    const int ke0 = k + quad;
    const int ke1 = k + 4 + quad;
    const int kc0 = min(ke0, end - 1);
    const int kc1 = min(ke1, end - 1);
    const int2 p0 = pairs[kc0];   // quad-uniform -> broadcast
    const int2 p1 = pairs[kc1];
    const bool v0 = ke0 < end;    // uniform within a quad
    const bool v1 = ke1 < end;

    FragU a00, a01, a10, a11, b0, b1;
    const ushort* xr0 = xt + (size_t)p0.x * 256;
    const ushort* xr1 = xt + (size_t)p1.x * 256;
    a00.u4 = *(const uint4*)(xr0 + nn * 8);          // b = nn
    a01.u4 = *(const uint4*)(xr0 + (16 + nn) * 8);   // b = 16+nn
    a10.u4 = *(const uint4*)(xr1 + nn * 8);
    a11.u4 = *(const uint4*)(xr1 + (16 + nn) * 8);

    b0.u4 = make_uint4(0, 0, 0, 0);
    b1.u4 = make_uint4(0, 0, 0, 0);
    if (nn < 8) {
      if (v0) {
        const float* vp = vals + (size_t)p0.y * 64 + nn;   // column j = nn
#pragma unroll
        for (int v = 0; v < 8; ++v) b0.us[v] = f2bf(vp[v * 8]);
      }
      if (v1) {
        const float* vp = vals + (size_t)p1.y * 64 + nn;
#pragma unroll
        for (int v = 0; v < 8; ++v) b1.us[v] = f2bf(vp[v * 8]);
      }
    }
    acc0 = __builtin_amdgcn_mfma_f32_16x16x32_bf16(a00.v, b0.v, acc0, 0, 0, 0);
    acc1 = __builtin_amdgcn_mfma_f32_16x16x32_bf16(a01.v, b0.v, acc1, 0, 0, 0);
    acc0 = __builtin_amdgcn_mfma_f32_16x16x32_bf16(a10.v, b1.v, acc0, 0, 0, 0);
    acc1 = __builtin_amdgcn_mfma_f32_16x16x32_bf16(a11.v, b1.v, acc1, 0, 0, 0);
  }

  // C/D: col(j) = lane&15, row(b) = quad*4 + reg
  if (nn < 8) {
    float bz = bias[n * 8 + nn];
#pragma unroll
    for (int r = 0; r < 4; ++r) {
      out[(size_t)(quad * 4 + r) * SIZE2 + n * 8 + nn] = acc0[r] + bz;
      out[(size_t)(16 + quad * 4 + r) * SIZE2 + n * 8 + nn] = acc1[r] + bz;
    }
  }
}

extern "C" void kernel_launch(void* const* d_in, const int* in_sizes, int n_in,
                              void* d_out, int out_size, void* d_ws, size_t ws_size,
                              hipStream_t stream) {
  const float* x    = (const float*)d_in[0];
  const float* vals = (const float*)d_in[1];
  const float* bias = (const float*)d_in[2];
  const int*   idxs = (const int*)d_in[3];
  float* out = (float*)d_out;

  int* ws = (int*)d_ws;
  int2* pairs    = (int2*)(ws + WS_PAIRS);
  int* counts    = ws + WS_COUNTS;
  int* offsets   = ws + WS_OFFSETS;
  int* cursor    = ws + WS_CURSOR;
  int* bsums     = ws + WS_BSUMS;
  ushort* xt     = (ushort*)(ws + WS_XT);

  hipMemsetAsync(counts, 0, N_NODES * sizeof(int), stream);

  const int egrid = (NE + 255) / 256;          // 1250
  const int ngrid = (N_NODES + 255) / 256;     // 40
  prep_kernel<<<egrid, 256, 0, stream>>>(x, xt, idxs, counts);
  scanA_kernel<<<ngrid, 256, 0, stream>>>(counts, offsets, bsums);
  scanC_kernel<<<ngrid, 256, 0, stream>>>(offsets, cursor, bsums);
  scatter_kernel<<<egrid, 256, 0, stream>>>(idxs, cursor, pairs);
  gather_mfma_kernel<<<N_NODES / 4, 256, 0, stream>>>(xt, vals, bias, offsets, pairs, out);
}

// Round 5
// 200.096 us; speedup vs baseline: 3.0678x; 1.0146x over previous
//
#include <hip/hip_runtime.h>
#include <stddef.h>

#define N_NODES 10000
#define NE 320000
#define NB 32
#define SIZE1 80000
#define SIZE2 80000

// d_ws layout (int offsets)
#define WS_PAIRS   0          // int2[NE] -> 640000 ints
#define WS_COUNTS  640000     // 10000 ints
#define WS_OFFSETS 650000     // 10001 ints
#define WS_CURSOR  660002     // 10000 ints
#define WS_BSUMS   670016     // 64 ints
#define WS_XT      680000     // bf16 xt[N_NODES][32][8] = 1.28M ints

typedef short short8 __attribute__((ext_vector_type(8)));
typedef float floatx4 __attribute__((ext_vector_type(4)));
union FragU { short8 v; ushort us[8]; uint4 u4; };

__device__ inline ushort f2bf(float f) {
  union { float f; unsigned u; } c; c.f = f;
  unsigned u = c.u;
  u += 0x7fffu + ((u >> 16) & 1u);   // round-to-nearest-even
  return (ushort)(u >> 16);
}

// Fused: edge-count histogram (all 1250 blocks) + x fp32->bf16 transpose
// into xt[n][b][i] (blocks < 313, 32 nodes each).
__global__ __launch_bounds__(256) void prep_kernel(const float* __restrict__ x,
                                                   ushort* __restrict__ xt,
                                                   const int* __restrict__ idxs,
                                                   int* __restrict__ counts) {
  {
    int e = blockIdx.x * 256 + threadIdx.x;
    if (e < NE) atomicAdd(&counts[idxs[e]], 1);
  }
  if (blockIdx.x >= 313) return;   // block-uniform exit before any barrier
  __shared__ float s[32 * 260];    // [b][nl*8+i], padded row stride
  const int t = threadIdx.x;
  const int n0 = blockIdx.x * 32;
#pragma unroll
  for (int it = 0; it < 8; ++it) {
    int idx = it * 256 + t;            // [0,2048)
    int b = idx >> 6, q = idx & 63;
    int base = n0 * 8 + q * 4;
    float4 v = make_float4(0.f, 0.f, 0.f, 0.f);
    if (base < SIZE1) v = *(const float4*)&x[(size_t)b * SIZE1 + base];
    *(float4*)&s[b * 260 + q * 4] = v;
  }
  __syncthreads();
#pragma unroll
  for (int r = 0; r < 4; ++r) {
    int p = r * 256 + t;               // [0,1024)
    int nl = p >> 5, b = p & 31;
    int n = n0 + nl;
    if (n < N_NODES) {
      FragU f;
      const float* row = &s[b * 260 + nl * 8];
#pragma unroll
      for (int i = 0; i < 8; ++i) f.us[i] = f2bf(row[i]);
      *(uint4*)&xt[(size_t)n * 256 + b * 8] = f.u4;
    }
  }
}

__global__ __launch_bounds__(256) void scanA_kernel(const int* __restrict__ counts,
                                                    int* __restrict__ offsets,
                                                    int* __restrict__ bsums) {
  __shared__ int s[256];
  const int t = threadIdx.x;
  const int i = blockIdx.x * 256 + t;
  int c = (i < N_NODES) ? counts[i] : 0;
  s[t] = c;
  __syncthreads();
#pragma unroll
  for (int d = 1; d < 256; d <<= 1) {
    int v = (t >= d) ? s[t - d] : 0;
    __syncthreads();
    s[t] += v;
    __syncthreads();
  }
  if (i < N_NODES) offsets[i] = s[t] - c;
  if (t == 255) bsums[blockIdx.x] = s[255];
}

__global__ __launch_bounds__(256) void scanC_kernel(int* __restrict__ offsets,
                                                    int* __restrict__ cursor,
                                                    const int* __restrict__ bsums) {
  const int t = threadIdx.x;
  const int nb = blockIdx.x;
  const int i = nb * 256 + t;
  int p = 0;
  for (int w = 0; w < nb; ++w) p += bsums[w];
  if (i < N_NODES) {
    int v = offsets[i] + p;
    offsets[i] = v;
    cursor[i] = v;
  }
  if (i == 0) offsets[N_NODES] = NE;
}

__global__ __launch_bounds__(256) void scatter_kernel(const int* __restrict__ idxs,
                                                      int* __restrict__ cursor,
                                                      int2* __restrict__ pairs) {
  int e = blockIdx.x * 256 + threadIdx.x;
  if (e < NE) {
    int r = idxs[e];
    int c = idxs[NE + e];
    int pos = atomicAdd(&cursor[r], 1);
    pairs[pos] = make_int2(c, e);
  }
}

// One wave per node; 16 edges per inner iteration (4 MFMA slots of 4 edges).
// K=32 packs 4 edges per MFMA: quad q's k-slots 8q..8q+7 hold slot-edge q.
// pairs for the whole node preloaded in ONE coalesced load (chunks of 64),
// broadcast per-slot via __shfl -> no serial pairs->data chain per iteration.
__global__ __launch_bounds__(256) void gather_mfma_kernel(const ushort* __restrict__ xt,
                                                          const float* __restrict__ vals,
                                                          const float* __restrict__ bias,
                                                          const int* __restrict__ offsets,
                                                          const int2* __restrict__ pairs,
                                                          float* __restrict__ out) {
  const int t = threadIdx.x;
  const int lane = t & 63;
  const int n = blockIdx.x * 4 + (t >> 6);   // 2500*4 = 10000
  const int quad = lane >> 4;
  const int nn = lane & 15;
  const int beg = offsets[n];
  const int end = offsets[n + 1];

  floatx4 acc0 = {0.f, 0.f, 0.f, 0.f};
  floatx4 acc1 = {0.f, 0.f, 0.f, 0.f};

  for (int base = beg; base < end; base += 64) {
    const int lim = min(64, end - base);                 // edges in this chunk
    int2 pv = pairs[min(base + lane, end - 1)];          // one coalesced load

    for (int it = 0; it < lim; it += 16) {
      FragU alo[4], ahi[4], bq[4];
      int valid[4];
#pragma unroll
      for (int s = 0; s < 4; ++s) {
        const int le = it + s * 4 + quad;                // local edge index
        const int lec = min(le, lim - 1);
        const int px = __shfl(pv.x, lec);                // quad-uniform col
        const int pe = __shfl(pv.y, lec);                // quad-uniform e
        valid[s] = le < lim;
        const ushort* xr = xt + (size_t)px * 256;
        alo[s].u4 = *(const uint4*)(xr + nn * 8);        // b = nn
        ahi[s].u4 = *(const uint4*)(xr + (16 + nn) * 8); // b = 16+nn
        bq[s].u4 = make_uint4(0, 0, 0, 0);
        if (nn < 8 && valid[s]) {
          const float* vp = vals + (size_t)pe * 64 + nn; // column j = nn
#pragma unroll
          for (int v = 0; v < 8; ++v) bq[s].us[v] = f2bf(vp[v * 8]);
        }
      }
#pragma unroll
      for (int s = 0; s < 4; ++s) {
        acc0 = __builtin_amdgcn_mfma_f32_16x16x32_bf16(alo[s].v, bq[s].v, acc0, 0, 0, 0);
        acc1 = __builtin_amdgcn_mfma_f32_16x16x32_bf16(ahi[s].v, bq[s].v, acc1, 0, 0, 0);
      }
    }
  }

  // C/D: col(j) = lane&15, row(b) = quad*4 + reg
  if (nn < 8) {
    float bz = bias[n * 8 + nn];
#pragma unroll
    for (int r = 0; r < 4; ++r) {
      out[(size_t)(quad * 4 + r) * SIZE2 + n * 8 + nn] = acc0[r] + bz;
      out[(size_t)(16 + quad * 4 + r) * SIZE2 + n * 8 + nn] = acc1[r] + bz;
    }
  }
}

extern "C" void kernel_launch(void* const* d_in, const int* in_sizes, int n_in,
                              void* d_out, int out_size, void* d_ws, size_t ws_size,
                              hipStream_t stream) {
  const float* x    = (const float*)d_in[0];
  const float* vals = (const float*)d_in[1];
  const float* bias = (const float*)d_in[2];
  const int*   idxs = (const int*)d_in[3];
  float* out = (float*)d_out;

  int* ws = (int*)d_ws;
  int2* pairs    = (int2*)(ws + WS_PAIRS);
  int* counts    = ws + WS_COUNTS;
  int* offsets   = ws + WS_OFFSETS;
  int* cursor    = ws + WS_CURSOR;
  int* bsums     = ws + WS_BSUMS;
  ushort* xt     = (ushort*)(ws + WS_XT);

  hipMemsetAsync(counts, 0, N_NODES * sizeof(int), stream);

  const int egrid = (NE + 255) / 256;          // 1250
  const int ngrid = (N_NODES + 255) / 256;     // 40
  prep_kernel<<<egrid, 256, 0, stream>>>(x, xt, idxs, counts);
  scanA_kernel<<<ngrid, 256, 0, stream>>>(counts, offsets, bsums);
  scanC_kernel<<<ngrid, 256, 0, stream>>>(offsets, cursor, bsums);
  scatter_kernel<<<egrid, 256, 0, stream>>>(idxs, cursor, pairs);
  gather_mfma_kernel<<<N_NODES / 4, 256, 0, stream>>>(xt, vals, bias, offsets, pairs, out);
}